// Round 9
// baseline (554.486 us; speedup 1.0000x reference)
//
#include <hip/hip_runtime.h>
#include <stdint.h>

#define MAX_DEG   10
#define DEG_COUNT 30000
#define N_ATOMS   330000      // 11 * 30000
#define NF        128
#define BATCH     128
#define SORT_BLOCKS 256

typedef __attribute__((ext_vector_type(8))) short bf16x8;   // 8 bf16 (4 VGPRs)
typedef __attribute__((ext_vector_type(4))) float f32x4;

__device__ __forceinline__ float bf2f(unsigned short h) {
  union { unsigned u; float f; } v; v.u = ((unsigned)h) << 16; return v.f;
}
__device__ __forceinline__ unsigned short f2bf(float f) {
  union { float f; unsigned u; } v; v.f = f;
  unsigned u = v.u;
  unsigned r = (u + 0x7fffu + ((u >> 16) & 1u)) >> 16;   // RNE
  return (unsigned short)r;
}

struct AdjPtrs { const int* p[10]; };

#define NEG_INF_BITS 0xFF800000

// ---------------------------------------------------------------------------
// K0: cast fp32 atoms -> bf16 copy (GEMM A-source + gather source)
// ---------------------------------------------------------------------------
__global__ __launch_bounds__(256) void k_cast(const float4* __restrict__ src,
                                              ushort4* __restrict__ dst) {
  size_t i = (size_t)blockIdx.x * 256 + threadIdx.x;   // one float4 -> ushort4
  float4 v = src[i];
  ushort4 o;
  o.x = f2bf(v.x); o.y = f2bf(v.y); o.z = f2bf(v.z); o.w = f2bf(v.w);
  dst[i] = o;
}

// ---------------------------------------------------------------------------
// K1a: build BcatT[d][n][k] (bf16), n in [0,128) (ACTIVATED half only; the
// gathered half is now computed algebraically in k_yn). k in [0,256):
// k<128 -> Wrel (deg>=1) | 0, k>=128 -> Wself (2d-1, or 20 for d=0).
// ---------------------------------------------------------------------------
__global__ __launch_bounds__(256) void k_build_b(const float* __restrict__ W,
                                                 unsigned short* __restrict__ BcatT) {
  int idx = blockIdx.x * 256 + threadIdx.x;
  if (idx >= 11 * 128 * 256) return;
  int d = idx >> 15;
  int rem = idx & 32767;
  int n = rem >> 8;          // 0..127
  int k = rem & 255;
  float v;
  if (k < 128) {
    v = (d >= 1) ? W[(2 * (d - 1)) * 16384 + k * 128 + n] : 0.f;
  } else {
    int ks = k - 128;
    int wi = (d >= 1) ? (2 * d - 1) : 20;
    v = W[wi * 16384 + ks * 128 + n];
  }
  BcatT[idx] = f2bf(v);   // idx == d*32768 + n*256 + k
}

// K1b: biascat[d][n] f32 (activated only): b_rel + b_self
__global__ __launch_bounds__(256) void k_build_bias(const float* __restrict__ b,
                                                    float* __restrict__ biascat) {
  int idx = blockIdx.x * 256 + threadIdx.x;
  if (idx >= 11 * 128) return;
  int d = idx >> 7, n = idx & 127;
  float f = (d >= 1) ? (b[(2 * (d - 1)) * 128 + n] + b[(2 * d - 1) * 128 + n])
                     : b[20 * 128 + n];
  biascat[idx] = f;
}

// ---------------------------------------------------------------------------
// Phase-0 helper (fused nsum): one wave computes 16 nsum rows of its block
// into LDS, 2 rows/iter (wave-coalesced gathers, 2D loads in flight).
// fp32 accumulate j-ascending + f2bf => bit-identical to old k_nsum.
// LDS rows XOR-swizzled (word ^= (row&7)<<2) for conflict-free af reads.
// ---------------------------------------------------------------------------
template<int D>
__device__ __forceinline__ void nsum_phase0(const unsigned* __restrict__ atomsU,
                                            const int* __restrict__ abase,
                                            unsigned* __restrict__ NS,
                                            int rowTile, int wave, int lane) {
  for (int it = 0; it < 8; ++it) {
    int iloc = wave * 16 + it * 2;               // local row 0..127
    int r0 = rowTile * 128 + iloc;
    int sw0 = lane ^ ((iloc & 7) << 2);
    int sw1 = lane ^ (((iloc + 1) & 7) << 2);
    if (r0 < DEG_COUNT - 1) {                    // normal pair (r0, r0+1)
      const int* a = abase + (size_t)r0 * D;
      int myIdx = (lane < 2 * D) ? a[lane] : 0;
      unsigned xs[2 * D];
#pragma unroll
      for (int j = 0; j < 2 * D; ++j) {
        int nbr = __shfl(myIdx, j, 64);
        xs[j] = atomsU[(size_t)nbr * 64 + lane];
      }
      float s0a = 0.f, s1a = 0.f, s0b = 0.f, s1b = 0.f;
#pragma unroll
      for (int j = 0; j < D; ++j) {
        s0a += bf2f((unsigned short)(xs[j] & 0xffff));
        s1a += bf2f((unsigned short)(xs[j] >> 16));
      }
#pragma unroll
      for (int j = D; j < 2 * D; ++j) {
        s0b += bf2f((unsigned short)(xs[j] & 0xffff));
        s1b += bf2f((unsigned short)(xs[j] >> 16));
      }
      NS[(size_t)iloc * 64 + sw0]       = (unsigned)f2bf(s0a) | ((unsigned)f2bf(s1a) << 16);
      NS[(size_t)(iloc + 1) * 64 + sw1] = (unsigned)f2bf(s0b) | ((unsigned)f2bf(s1b) << 16);
    } else {                                     // tail: both rows clamp to 29999
      const int* a = abase + (size_t)(DEG_COUNT - 1) * D;
      int myIdx = (lane < D) ? a[lane] : 0;
      unsigned xs[D];
#pragma unroll
      for (int j = 0; j < D; ++j) {
        int nbr = __shfl(myIdx, j, 64);
        xs[j] = atomsU[(size_t)nbr * 64 + lane];
      }
      float s0 = 0.f, s1 = 0.f;
#pragma unroll
      for (int j = 0; j < D; ++j) {
        s0 += bf2f((unsigned short)(xs[j] & 0xffff));
        s1 += bf2f((unsigned short)(xs[j] >> 16));
      }
      unsigned p = (unsigned)f2bf(s0) | ((unsigned)f2bf(s1) << 16);
      NS[(size_t)iloc * 64 + sw0] = p;
      NS[(size_t)(iloc + 1) * 64 + sw1] = p;
    }
  }
}

// ---------------------------------------------------------------------------
// K3: fused nsum + streaming MFMA GEMM — ACTIVATED half only (128 cols).
// 128 rows/block, 16 rows/wave, 64KB LDS, VGPR<=128 -> 2 blocks/CU (the
// round-8 failure was 1 block/CU: no TLP to hide phase-0 gather latency).
// ---------------------------------------------------------------------------
__global__ __launch_bounds__(512, 4) void k_gemm(
    const unsigned short* __restrict__ atomsBf,
    AdjPtrs adj,
    const unsigned short* __restrict__ BcatT,    // [11][128][256] n-major
    const float* __restrict__ biascat,           // [11][128]
    const float* __restrict__ gamma,
    const float* __restrict__ beta,
    float* __restrict__ out0)                    // xn FINAL (fp32)
{
  const int d = blockIdx.y;
  const int rowTile = blockIdx.x;
  const int tid = threadIdx.x;
  const int lane = tid & 63;
  const int wave = tid >> 6;          // 0..7
  const int m16 = lane & 15;
  const int g = lane >> 4;            // k-group 0..3

  __shared__ unsigned short Bs[128 * 256];   // 64 KiB; phase0 NS uses first 32KB
  unsigned* NS = (unsigned*)Bs;              // [128 rows][64 words], swizzled

  const unsigned short* Bd = BcatT + d * 32768;
  const unsigned* atomsU = (const unsigned*)atomsBf;

  // ---- self A-frags (ks 4-7) from global first (overlap with phase 0) ----
  const int rowBase = rowTile * 128 + wave * 16;
  bf16x8 af[8];
  {
    int rbL = rowBase + m16; if (rbL > DEG_COUNT - 1) rbL = DEG_COUNT - 1;
    size_t gr = (size_t)d * DEG_COUNT + rbL;
#pragma unroll
    for (int ks = 4; ks < 8; ++ks)
      af[ks] = *(const bf16x8*)(atomsBf + gr * 128 + (ks - 4) * 32 + g * 8);
  }

  // ---- phase 0: fused nsum into LDS; af ks0-3 from LDS ----
  if (d > 0) {
    const int* abase = adj.p[d - 1];
    switch (d) {
      case 1:  nsum_phase0<1>(atomsU, abase, NS, rowTile, wave, lane); break;
      case 2:  nsum_phase0<2>(atomsU, abase, NS, rowTile, wave, lane); break;
      case 3:  nsum_phase0<3>(atomsU, abase, NS, rowTile, wave, lane); break;
      case 4:  nsum_phase0<4>(atomsU, abase, NS, rowTile, wave, lane); break;
      case 5:  nsum_phase0<5>(atomsU, abase, NS, rowTile, wave, lane); break;
      case 6:  nsum_phase0<6>(atomsU, abase, NS, rowTile, wave, lane); break;
      case 7:  nsum_phase0<7>(atomsU, abase, NS, rowTile, wave, lane); break;
      case 8:  nsum_phase0<8>(atomsU, abase, NS, rowTile, wave, lane); break;
      case 9:  nsum_phase0<9>(atomsU, abase, NS, rowTile, wave, lane); break;
      default: nsum_phase0<10>(atomsU, abase, NS, rowTile, wave, lane); break;
    }
    __syncthreads();
    const char* nsb = (const char*)NS;
    const int rowb = (wave * 16 + m16) * 256;         // byte base, local row
    const int sw = (m16 & 7) << 4;
#pragma unroll
    for (int ks = 0; ks < 4; ++ks)
      af[ks] = *(const bf16x8*)(nsb + ((rowb + ks * 64 + g * 16) ^ sw));
    __syncthreads();   // protect NS before B-panel overwrite
  } else {
    bf16x8 z = {0, 0, 0, 0, 0, 0, 0, 0};
#pragma unroll
    for (int ks = 0; ks < 4; ++ks) af[ks] = z;
  }

  // ---- stage B: 512 threads x 8 x 16B = 64KB, swizzled dest ----
#pragma unroll
  for (int it = 0; it < 8; ++it) {
    int flat = it * 512 + tid;        // chunk of 16B; 32 chunks per row
    int row = flat >> 5;              // 0..127
    int c = flat & 31;
    uint4 v = *(const uint4*)(Bd + row * 256 + c * 8);
    int kb = (c * 16) ^ ((row & 7) << 4);
    *(uint4*)((char*)Bs + row * 512 + kb) = v;
  }

  __syncthreads();

  const int ldsMask = (m16 & 7) << 4;

  f32x4 acc[8];
#pragma unroll
  for (int ct = 0; ct < 8; ++ct) acc[ct] = (f32x4){0.f, 0.f, 0.f, 0.f};

#pragma unroll
  for (int ct = 0; ct < 8; ++ct) {
    const char* bbase = (const char*)Bs + (ct * 16 + m16) * 512;
    bf16x8 bf[8];
#pragma unroll
    for (int ks = 0; ks < 8; ++ks)
      bf[ks] = *(const bf16x8*)(bbase + ((ks * 64 + g * 16) ^ ldsMask));
#pragma unroll
    for (int ks = 0; ks < 8; ++ks)
      acc[ct] = __builtin_amdgcn_mfma_f32_16x16x32_bf16(af[ks], bf[ks], acc[ct], 0, 0, 0);
  }

  // ---- epilogue: bias, LN over 128 cols, coalesced stores ----
  float bias_[8], gam[8], bet[8];
#pragma unroll
  for (int ct = 0; ct < 8; ++ct) {
    bias_[ct] = biascat[d * 128 + ct * 16 + m16];
    gam[ct] = gamma[ct * 16 + m16];
    bet[ct] = beta[ct * 16 + m16];
  }

#pragma unroll
  for (int ct = 0; ct < 8; ++ct)
#pragma unroll
    for (int r = 0; r < 4; ++r) acc[ct][r] += bias_[ct];

  float s[4], qq[4];
#pragma unroll
  for (int r = 0; r < 4; ++r) {
    s[r] = 0.f; qq[r] = 0.f;
#pragma unroll
    for (int ct = 0; ct < 8; ++ct) {
      float v = acc[ct][r];
      s[r] += v; qq[r] += v * v;
    }
  }
#pragma unroll
  for (int off = 8; off >= 1; off >>= 1) {
#pragma unroll
    for (int r = 0; r < 4; ++r) {
      s[r]  += __shfl_xor(s[r],  off, 64);
      qq[r] += __shfl_xor(qq[r], off, 64);
    }
  }

#pragma unroll
  for (int r = 0; r < 4; ++r) {
    int rb = rowBase + g * 4 + r;
    float mean = s[r] * (1.0f / 128.0f);
    float var  = qq[r] * (1.0f / 128.0f) - mean * mean;
    float inv  = 1.0f / (sqrtf(var + 1e-5f) + 1e-5f);   // ref: sqrt(var+eps)+eps
    if (rb < DEG_COUNT) {
      size_t grow = (size_t)d * DEG_COUNT + rb;
#pragma unroll
      for (int ct = 0; ct < 8; ++ct)
        out0[grow * 128 + ct * 16 + m16] = gam[ct] * ((acc[ct][r] - mean) * inv) + bet[ct];
    }
  }
}

// ---------------------------------------------------------------------------
// Counting sort by membership — atomic-contention-free 3-phase version.
// ---------------------------------------------------------------------------
__global__ __launch_bounds__(256) void k_hist2(const int* __restrict__ membership,
                                               int* __restrict__ blockHist) {
  __shared__ int bins[BATCH];
  int tid = threadIdx.x;
  if (tid < BATCH) bins[tid] = 0;
  __syncthreads();
  const int chunk = (N_ATOMS + SORT_BLOCKS - 1) / SORT_BLOCKS;
  int lo = blockIdx.x * chunk, hi = min(lo + chunk, N_ATOMS);
  for (int i = lo + tid; i < hi; i += 256)
    atomicAdd(&bins[membership[i]], 1);
  __syncthreads();
  if (tid < BATCH) blockHist[blockIdx.x * BATCH + tid] = bins[tid];
}

__global__ __launch_bounds__(128) void k_scan2(const int* __restrict__ blockHist,
                                               int* __restrict__ off,     // [SORT_BLOCKS][128]
                                               int* __restrict__ base,
                                               int* __restrict__ hist) {
  int m = threadIdx.x;
  int tot = 0;
  for (int b = 0; b < SORT_BLOCKS; ++b) tot += blockHist[b * BATCH + m];
  hist[m] = tot;
  __shared__ int t[BATCH];
  t[m] = tot;
  __syncthreads();
  int acc = 0;
  for (int i = 0; i < m; ++i) acc += t[i];
  base[m] = acc;
  int run = acc;
  for (int b = 0; b < SORT_BLOCKS; ++b) {
    off[b * BATCH + m] = run;
    run += blockHist[b * BATCH + m];
  }
}

__global__ __launch_bounds__(256) void k_scatter2(const int* __restrict__ membership,
                                                  const int* __restrict__ off,
                                                  int* __restrict__ perm) {
  __shared__ int bins[BATCH];
  int tid = threadIdx.x;
  if (tid < BATCH) bins[tid] = off[blockIdx.x * BATCH + tid];
  __syncthreads();
  const int chunk = (N_ATOMS + SORT_BLOCKS - 1) / SORT_BLOCKS;
  int lo = blockIdx.x * chunk, hi = min(lo + chunk, N_ATOMS);
  for (int i = lo + tid; i < hi; i += 256) {
    int m = membership[i];
    int pos = atomicAdd(&bins[m], 1);
    perm[pos] = i;
  }
}

// ---------------------------------------------------------------------------
// K_msum: per-(molecule, degree) sums of bf16 atom rows + counts, via perm.
// 512 blocks = 128 molecules x 4 slices; wave-private LDS tables (no atomics;
// d is wave-uniform since all lanes share the row). Feeds the algebraic
// gathered-sum: seg_sum(self@Wg + bg) = S[m,d]@Wg_d + cnt[m,d]*bg_d.
// ---------------------------------------------------------------------------
__global__ __launch_bounds__(512) void k_msum(
    const unsigned* __restrict__ atomsU,
    const int* __restrict__ perm,
    const int* __restrict__ base,
    const int* __restrict__ hist,
    float* __restrict__ Spart,      // [4][128][11][128]
    int* __restrict__ cntPart)      // [4][128][11]
{
  const int m = blockIdx.x >> 2;
  const int s = blockIdx.x & 3;
  const int b0 = base[m], cnt = hist[m];
  const int lo = b0 + (cnt * s) / 4;
  const int hi = b0 + (cnt * (s + 1)) / 4;
  const int wave = threadIdx.x >> 6, lane = threadIdx.x & 63;

  __shared__ float S[8][11][128];   // physical col p: p<64 -> col 2p, else 2(p-64)+1
  __shared__ int C[8][11];
  for (int e = lane; e < 11 * 128; e += 64) S[wave][e >> 7][e & 127] = 0.f;
  if (lane < 11) C[wave][lane] = 0;
  __syncthreads();

  for (int i = lo + wave; i < hi; i += 8) {
    int r = perm[i];
    int d = r / DEG_COUNT;                      // wave-uniform
    unsigned x = atomsU[(size_t)r * 64 + lane];
    S[wave][d][lane]      += bf2f((unsigned short)(x & 0xffff));
    S[wave][d][64 + lane] += bf2f((unsigned short)(x >> 16));
    if (lane == 0) C[wave][d]++;
  }
  __syncthreads();

  for (int e = threadIdx.x; e < 11 * 128; e += 512) {
    int d = e >> 7, p = e & 127;
    float t = 0.f;
#pragma unroll
    for (int w = 0; w < 8; ++w) t += S[w][d][p];
    int col = (p < 64) ? (2 * p) : (2 * (p - 64) + 1);   // de-permute
    Spart[(((size_t)s * 128 + m) * 11 + d) * 128 + col] = t;
  }
  if (threadIdx.x < 11) {
    int t = 0;
#pragma unroll
    for (int w = 0; w < 8; ++w) t += C[w][threadIdx.x];
    cntPart[((size_t)s * 128 + m) * 11 + threadIdx.x] = t;
  }
}

// ---------------------------------------------------------------------------
// K_yn: yn = LN( sum_d S[m,d] @ Wg_d + cnt[m,d]*bg_d ). All fp32 (more
// accurate than the old bf16 gathered round-trip). 128 blocks x 128 threads.
// ---------------------------------------------------------------------------
__global__ __launch_bounds__(128) void k_yn(
    const float* __restrict__ Spart,
    const int* __restrict__ cntPart,
    const float* __restrict__ W,
    const float* __restrict__ b,
    const float* __restrict__ gamma,
    const float* __restrict__ beta,
    float* __restrict__ out1)
{
  int m = blockIdx.x;
  int j = threadIdx.x;
  __shared__ float Sm[11][128];
  __shared__ float cw[11];
  for (int e = j; e < 11 * 128; e += 128) {
    int d = e >> 7, c = e & 127;
    float t = 0.f;
#pragma unroll
    for (int sl = 0; sl < 4; ++sl)
      t += Spart[(((size_t)sl * 128 + m) * 11 + d) * 128 + c];
    Sm[d][c] = t;
  }
  if (j < 11) {
    int t = 0;
#pragma unroll
    for (int sl = 0; sl < 4; ++sl) t += cntPart[((size_t)sl * 128 + m) * 11 + j];
    cw[j] = (float)t;
  }
  __syncthreads();

  float acc = 0.f;
  for (int d = 0; d < 11; ++d) {
    int wi = (d >= 1) ? (20 + d) : 31;
    const float* Wd = W + wi * 16384;
    float a0 = 0.f, a1 = 0.f, a2 = 0.f, a3 = 0.f;
    for (int k = 0; k < 128; k += 4) {
      a0 += Sm[d][k]     * Wd[k * 128 + j];
      a1 += Sm[d][k + 1] * Wd[(k + 1) * 128 + j];
      a2 += Sm[d][k + 2] * Wd[(k + 2) * 128 + j];
      a3 += Sm[d][k + 3] * Wd[(k + 3) * 128 + j];
    }
    acc += (a0 + a1) + (a2 + a3);
    acc += cw[d] * b[wi * 128 + j];
  }

  float ws_ = acc, wq = acc * acc;
#pragma unroll
  for (int off = 32; off >= 1; off >>= 1) {
    ws_ += __shfl_xor(ws_, off, 64);
    wq  += __shfl_xor(wq, off, 64);
  }
  __shared__ float red[4];
  int wave = j >> 6, lane = j & 63;
  if (lane == 0) { red[wave * 2] = ws_; red[wave * 2 + 1] = wq; }
  __syncthreads();
  float Ssum = red[0] + red[2], Q = red[1] + red[3];
  float mean = Ssum * (1.f / 128.f);
  float var = Q * (1.f / 128.f) - mean * mean;
  float inv = 1.f / (sqrtf(var + 1e-5f) + 1e-5f);
  out1[m * 128 + j] = gamma[j] * ((acc - mean) * inv) + beta[j];
}

// ---------------------------------------------------------------------------
// K_reduce: segment-max(xn) only (sum path replaced by k_msum/k_yn).
// ---------------------------------------------------------------------------
__global__ __launch_bounds__(512) void k_reduce(
    const float2* __restrict__ xnV,
    const int* __restrict__ perm,
    const int* __restrict__ base,
    const int* __restrict__ hist,
    float2* __restrict__ pmax4)             // [4][128][64] float2
{
  const int m = blockIdx.x >> 2;
  const int s = blockIdx.x & 3;
  const int b0 = base[m], cnt = hist[m];
  const int lo = b0 + (cnt * s) / 4;
  const int hi = b0 + (cnt * (s + 1)) / 4;
  const int wave = threadIdx.x >> 6, lane = threadIdx.x & 63;

  const float NEG_INF = __int_as_float((int)NEG_INF_BITS);
  float mx0 = NEG_INF, mx1 = NEG_INF;

#pragma unroll 4
  for (int i = lo + wave; i < hi; i += 8) {
    int r = perm[i];
    float2 x = xnV[(size_t)r * 64 + lane];
    mx0 = fmaxf(mx0, x.x);
    mx1 = fmaxf(mx1, x.y);
  }

  __shared__ float2 maxT[8][64];
  maxT[wave][lane] = make_float2(mx0, mx1);
  __syncthreads();

  if (threadIdx.x < 64) {
    int l = threadIdx.x;
    float2 mm = maxT[0][l];
#pragma unroll
    for (int w = 1; w < 8; ++w) {
      float2 b = maxT[w][l]; mm.x = fmaxf(mm.x, b.x); mm.y = fmaxf(mm.y, b.y);
    }
    pmax4[(s * 128 + m) * 64 + l] = mm;
  }
}

// K6: merge 4 max slices -> g (out2).
__global__ __launch_bounds__(128) void k_final(
    const float* __restrict__ pmax4,        // [4][128][128]
    float* __restrict__ out2)
{
  int m = blockIdx.x;
  int j = threadIdx.x;
  float g = __int_as_float((int)NEG_INF_BITS);
#pragma unroll
  for (int sl = 0; sl < 4; ++sl)
    g = fmaxf(g, pmax4[(sl * 128 + m) * 128 + j]);
  out2[m * 128 + j] = g;
}

// ---------------------------------------------------------------------------
extern "C" void kernel_launch(void* const* d_in, const int* in_sizes, int n_in,
                              void* d_out, int out_size, void* d_ws, size_t ws_size,
                              hipStream_t stream) {
  const float* atoms = (const float*)d_in[0];
  // d_in[1] = deg_slice (unused; buckets are static)
  const int* membership = (const int*)d_in[2];
  AdjPtrs adj;
  for (int i = 0; i < 10; ++i) adj.p[i] = (const int*)d_in[3 + i];
  const float* W     = (const float*)d_in[13];
  const float* b     = (const float*)d_in[14];
  const float* gamma = (const float*)d_in[15];
  const float* beta  = (const float*)d_in[16];

  char* ws = (char*)d_ws;
  size_t off = 0;
  unsigned short* atomsBf = (unsigned short*)(ws + off); off += (size_t)N_ATOMS * 128 * 2;
  unsigned short* BcatT   = (unsigned short*)(ws + off); off += (size_t)11 * 128 * 256 * 2;
  float* biascat          = (float*)(ws + off);          off += (size_t)11 * 128 * 4;
  int* perm               = (int*)(ws + off);            off += (size_t)N_ATOMS * 4;
  int* hist               = (int*)(ws + off);            off += 512;
  int* base_              = (int*)(ws + off);            off += 512;
  int* blockHist          = (int*)(ws + off);            off += (size_t)SORT_BLOCKS * BATCH * 4;
  int* offTab             = (int*)(ws + off);            off += (size_t)SORT_BLOCKS * BATCH * 4;
  float* Spart            = (float*)(ws + off);          off += (size_t)4 * 128 * 11 * 128 * 4;
  int* cntPart            = (int*)(ws + off);            off += (size_t)4 * 128 * 11 * 4;
  float* pmax4            = (float*)(ws + off);          off += (size_t)4 * 128 * 128 * 4;

  float* out0 = (float*)d_out;
  float* out1 = out0 + (size_t)N_ATOMS * 128;
  float* out2 = out1 + 16384;

  hipLaunchKernelGGL(k_cast, dim3(N_ATOMS * 128 / 4 / 256), dim3(256), 0, stream,
                     (const float4*)atoms, (ushort4*)atomsBf);
  hipLaunchKernelGGL(k_build_b, dim3((11 * 128 * 256 + 255) / 256), dim3(256), 0, stream, W, BcatT);
  hipLaunchKernelGGL(k_build_bias, dim3((11 * 128 + 255) / 256), dim3(256), 0, stream, b, biascat);
  // counting sort (own scratch; zero global atomics)
  hipLaunchKernelGGL(k_hist2, dim3(SORT_BLOCKS), dim3(256), 0, stream, membership, blockHist);
  hipLaunchKernelGGL(k_scan2, dim3(1), dim3(128), 0, stream, blockHist, offTab, base_, hist);
  hipLaunchKernelGGL(k_scatter2, dim3(SORT_BLOCKS), dim3(256), 0, stream, membership, offTab, perm);
  // per-(molecule,degree) atom sums for the algebraic gathered path
  hipLaunchKernelGGL(k_msum, dim3(512), dim3(512), 0, stream,
                     (const unsigned*)atomsBf, perm, base_, hist, Spart, cntPart);
  // fused nsum + activated GEMM + LN
  hipLaunchKernelGGL(k_gemm, dim3(236, 11), dim3(512), 0, stream,
                     atomsBf, adj, BcatT, biascat, gamma, beta, out0);
  // segment max of xn
  hipLaunchKernelGGL(k_reduce, dim3(512), dim3(512), 0, stream,
                     (const float2*)out0, perm, base_, hist, (float2*)pmax4);
  // yn via tiny fp32 GEMM + LN
  hipLaunchKernelGGL(k_yn, dim3(128), dim3(128), 0, stream,
                     Spart, cntPart, W, b, gamma, beta, out1);
  hipLaunchKernelGGL(k_final, dim3(128), dim3(128), 0, stream, pmax4, out2);
}

// Round 10
// 552.026 us; speedup vs baseline: 1.0045x; 1.0045x over previous
//
#include <hip/hip_runtime.h>
#include <stdint.h>

#define MAX_DEG   10
#define DEG_COUNT 30000
#define N_ATOMS   330000      // 11 * 30000
#define NF        128
#define BATCH     128
#define SORT_BLOCKS 256

typedef __attribute__((ext_vector_type(8))) short bf16x8;   // 8 bf16 (4 VGPRs)
typedef __attribute__((ext_vector_type(4))) float f32x4;
typedef __attribute__((ext_vector_type(2))) float f32x2;

__device__ __forceinline__ float bf2f(unsigned short h) {
  union { unsigned u; float f; } v; v.u = ((unsigned)h) << 16; return v.f;
}
__device__ __forceinline__ unsigned short f2bf(float f) {
  union { float f; unsigned u; } v; v.f = f;
  unsigned u = v.u;
  unsigned r = (u + 0x7fffu + ((u >> 16) & 1u)) >> 16;   // RNE
  return (unsigned short)r;
}

struct AdjPtrs { const int* p[10]; };

#define NEG_INF_BITS 0xFF800000

// ---------------------------------------------------------------------------
// K0: cast fp32 atoms -> bf16 copy. nt-load the read-once fp32 source so it
// doesn't evict anything; the bf16 copy stays cacheable (heavily re-read).
// ---------------------------------------------------------------------------
__global__ __launch_bounds__(256) void k_cast(const f32x4* __restrict__ src,
                                              ushort4* __restrict__ dst) {
  size_t i = (size_t)blockIdx.x * 256 + threadIdx.x;   // one float4 -> ushort4
  f32x4 v = __builtin_nontemporal_load(src + i);
  ushort4 o;
  o.x = f2bf(v[0]); o.y = f2bf(v[1]); o.z = f2bf(v[2]); o.w = f2bf(v[3]);
  dst[i] = o;
}

// ---------------------------------------------------------------------------
// K1a: build BcatT[d][n][k] (bf16), n in [0,128) (activated half only).
// k<128 -> Wrel (deg>=1) | 0, k>=128 -> Wself (2d-1, or 20 for d=0).
// ---------------------------------------------------------------------------
__global__ __launch_bounds__(256) void k_build_b(const float* __restrict__ W,
                                                 unsigned short* __restrict__ BcatT) {
  int idx = blockIdx.x * 256 + threadIdx.x;
  if (idx >= 11 * 128 * 256) return;
  int d = idx >> 15;
  int rem = idx & 32767;
  int n = rem >> 8;          // 0..127
  int k = rem & 255;
  float v;
  if (k < 128) {
    v = (d >= 1) ? W[(2 * (d - 1)) * 16384 + k * 128 + n] : 0.f;
  } else {
    int ks = k - 128;
    int wi = (d >= 1) ? (2 * d - 1) : 20;
    v = W[wi * 16384 + ks * 128 + n];
  }
  BcatT[idx] = f2bf(v);   // idx == d*32768 + n*256 + k
}

// K1b: biascat[d][n] f32 (activated only): b_rel + b_self
__global__ __launch_bounds__(256) void k_build_bias(const float* __restrict__ b,
                                                    float* __restrict__ biascat) {
  int idx = blockIdx.x * 256 + threadIdx.x;
  if (idx >= 11 * 128) return;
  int d = idx >> 7, n = idx & 127;
  float f = (d >= 1) ? (b[(2 * (d - 1)) * 128 + n] + b[(2 * d - 1) * 128 + n])
                     : b[20 * 128 + n];
  biascat[idx] = f;
}

// ---------------------------------------------------------------------------
// Phase-0 helper (fused nsum): one wave computes 16 nsum rows of its block
// into LDS, 2 rows/iter (wave-coalesced gathers, 2D loads in flight).
// fp32 accumulate j-ascending + f2bf => bit-identical to old k_nsum.
// LDS rows XOR-swizzled (word ^= (row&7)<<2) for conflict-free af reads.
// ---------------------------------------------------------------------------
template<int D>
__device__ __forceinline__ void nsum_phase0(const unsigned* __restrict__ atomsU,
                                            const int* __restrict__ abase,
                                            unsigned* __restrict__ NS,
                                            int rowTile, int wave, int lane) {
  for (int it = 0; it < 8; ++it) {
    int iloc = wave * 16 + it * 2;               // local row 0..127
    int r0 = rowTile * 128 + iloc;
    int sw0 = lane ^ ((iloc & 7) << 2);
    int sw1 = lane ^ (((iloc + 1) & 7) << 2);
    if (r0 < DEG_COUNT - 1) {                    // normal pair (r0, r0+1)
      const int* a = abase + (size_t)r0 * D;
      int myIdx = (lane < 2 * D) ? a[lane] : 0;
      unsigned xs[2 * D];
#pragma unroll
      for (int j = 0; j < 2 * D; ++j) {
        int nbr = __shfl(myIdx, j, 64);
        xs[j] = atomsU[(size_t)nbr * 64 + lane];
      }
      float s0a = 0.f, s1a = 0.f, s0b = 0.f, s1b = 0.f;
#pragma unroll
      for (int j = 0; j < D; ++j) {
        s0a += bf2f((unsigned short)(xs[j] & 0xffff));
        s1a += bf2f((unsigned short)(xs[j] >> 16));
      }
#pragma unroll
      for (int j = D; j < 2 * D; ++j) {
        s0b += bf2f((unsigned short)(xs[j] & 0xffff));
        s1b += bf2f((unsigned short)(xs[j] >> 16));
      }
      NS[(size_t)iloc * 64 + sw0]       = (unsigned)f2bf(s0a) | ((unsigned)f2bf(s1a) << 16);
      NS[(size_t)(iloc + 1) * 64 + sw1] = (unsigned)f2bf(s0b) | ((unsigned)f2bf(s1b) << 16);
    } else {                                     // tail: both rows clamp to 29999
      const int* a = abase + (size_t)(DEG_COUNT - 1) * D;
      int myIdx = (lane < D) ? a[lane] : 0;
      unsigned xs[D];
#pragma unroll
      for (int j = 0; j < D; ++j) {
        int nbr = __shfl(myIdx, j, 64);
        xs[j] = atomsU[(size_t)nbr * 64 + lane];
      }
      float s0 = 0.f, s1 = 0.f;
#pragma unroll
      for (int j = 0; j < D; ++j) {
        s0 += bf2f((unsigned short)(xs[j] & 0xffff));
        s1 += bf2f((unsigned short)(xs[j] >> 16));
      }
      unsigned p = (unsigned)f2bf(s0) | ((unsigned)f2bf(s1) << 16);
      NS[(size_t)iloc * 64 + sw0] = p;
      NS[(size_t)(iloc + 1) * 64 + sw1] = p;
    }
  }
}

// ---------------------------------------------------------------------------
// K3: fused nsum + streaming MFMA GEMM — activated half (128 cols), 128
// rows/block, 2 blocks/CU. NEW: out0 stores are NON-TEMPORAL — out0 is
// write-once (re-read only once, later, by k_mreduce), and its 165MB stream
// was evicting the 84.5MB atomsBf gather working set from L3 (FETCH was
// 246MB vs 85MB distinct).
// ---------------------------------------------------------------------------
__global__ __launch_bounds__(512, 4) void k_gemm(
    const unsigned short* __restrict__ atomsBf,
    AdjPtrs adj,
    const unsigned short* __restrict__ BcatT,    // [11][128][256] n-major
    const float* __restrict__ biascat,           // [11][128]
    const float* __restrict__ gamma,
    const float* __restrict__ beta,
    float* __restrict__ out0)                    // xn FINAL (fp32)
{
  const int d = blockIdx.y;
  const int rowTile = blockIdx.x;
  const int tid = threadIdx.x;
  const int lane = tid & 63;
  const int wave = tid >> 6;          // 0..7
  const int m16 = lane & 15;
  const int g = lane >> 4;            // k-group 0..3

  __shared__ unsigned short Bs[128 * 256];   // 64 KiB; phase0 NS uses first 32KB
  unsigned* NS = (unsigned*)Bs;              // [128 rows][64 words], swizzled

  const unsigned short* Bd = BcatT + d * 32768;
  const unsigned* atomsU = (const unsigned*)atomsBf;

  // ---- self A-frags (ks 4-7) from global first (overlap with phase 0) ----
  const int rowBase = rowTile * 128 + wave * 16;
  bf16x8 af[8];
  {
    int rbL = rowBase + m16; if (rbL > DEG_COUNT - 1) rbL = DEG_COUNT - 1;
    size_t gr = (size_t)d * DEG_COUNT + rbL;
#pragma unroll
    for (int ks = 4; ks < 8; ++ks)
      af[ks] = *(const bf16x8*)(atomsBf + gr * 128 + (ks - 4) * 32 + g * 8);
  }

  // ---- phase 0: fused nsum into LDS; af ks0-3 from LDS ----
  if (d > 0) {
    const int* abase = adj.p[d - 1];
    switch (d) {
      case 1:  nsum_phase0<1>(atomsU, abase, NS, rowTile, wave, lane); break;
      case 2:  nsum_phase0<2>(atomsU, abase, NS, rowTile, wave, lane); break;
      case 3:  nsum_phase0<3>(atomsU, abase, NS, rowTile, wave, lane); break;
      case 4:  nsum_phase0<4>(atomsU, abase, NS, rowTile, wave, lane); break;
      case 5:  nsum_phase0<5>(atomsU, abase, NS, rowTile, wave, lane); break;
      case 6:  nsum_phase0<6>(atomsU, abase, NS, rowTile, wave, lane); break;
      case 7:  nsum_phase0<7>(atomsU, abase, NS, rowTile, wave, lane); break;
      case 8:  nsum_phase0<8>(atomsU, abase, NS, rowTile, wave, lane); break;
      case 9:  nsum_phase0<9>(atomsU, abase, NS, rowTile, wave, lane); break;
      default: nsum_phase0<10>(atomsU, abase, NS, rowTile, wave, lane); break;
    }
    __syncthreads();
    const char* nsb = (const char*)NS;
    const int rowb = (wave * 16 + m16) * 256;         // byte base, local row
    const int sw = (m16 & 7) << 4;
#pragma unroll
    for (int ks = 0; ks < 4; ++ks)
      af[ks] = *(const bf16x8*)(nsb + ((rowb + ks * 64 + g * 16) ^ sw));
    __syncthreads();   // protect NS before B-panel overwrite
  } else {
    bf16x8 z = {0, 0, 0, 0, 0, 0, 0, 0};
#pragma unroll
    for (int ks = 0; ks < 4; ++ks) af[ks] = z;
  }

  // ---- stage B: 512 threads x 8 x 16B = 64KB, swizzled dest ----
#pragma unroll
  for (int it = 0; it < 8; ++it) {
    int flat = it * 512 + tid;        // chunk of 16B; 32 chunks per row
    int row = flat >> 5;              // 0..127
    int c = flat & 31;
    uint4 v = *(const uint4*)(Bd + row * 256 + c * 8);
    int kb = (c * 16) ^ ((row & 7) << 4);
    *(uint4*)((char*)Bs + row * 512 + kb) = v;
  }

  __syncthreads();

  const int ldsMask = (m16 & 7) << 4;

  f32x4 acc[8];
#pragma unroll
  for (int ct = 0; ct < 8; ++ct) acc[ct] = (f32x4){0.f, 0.f, 0.f, 0.f};

#pragma unroll
  for (int ct = 0; ct < 8; ++ct) {
    const char* bbase = (const char*)Bs + (ct * 16 + m16) * 512;
    bf16x8 bf[8];
#pragma unroll
    for (int ks = 0; ks < 8; ++ks)
      bf[ks] = *(const bf16x8*)(bbase + ((ks * 64 + g * 16) ^ ldsMask));
#pragma unroll
    for (int ks = 0; ks < 8; ++ks)
      acc[ct] = __builtin_amdgcn_mfma_f32_16x16x32_bf16(af[ks], bf[ks], acc[ct], 0, 0, 0);
  }

  // ---- epilogue: bias, LN over 128 cols, NON-TEMPORAL coalesced stores ----
  float bias_[8], gam[8], bet[8];
#pragma unroll
  for (int ct = 0; ct < 8; ++ct) {
    bias_[ct] = biascat[d * 128 + ct * 16 + m16];
    gam[ct] = gamma[ct * 16 + m16];
    bet[ct] = beta[ct * 16 + m16];
  }

#pragma unroll
  for (int ct = 0; ct < 8; ++ct)
#pragma unroll
    for (int r = 0; r < 4; ++r) acc[ct][r] += bias_[ct];

  float s[4], qq[4];
#pragma unroll
  for (int r = 0; r < 4; ++r) {
    s[r] = 0.f; qq[r] = 0.f;
#pragma unroll
    for (int ct = 0; ct < 8; ++ct) {
      float v = acc[ct][r];
      s[r] += v; qq[r] += v * v;
    }
  }
#pragma unroll
  for (int off = 8; off >= 1; off >>= 1) {
#pragma unroll
    for (int r = 0; r < 4; ++r) {
      s[r]  += __shfl_xor(s[r],  off, 64);
      qq[r] += __shfl_xor(qq[r], off, 64);
    }
  }

#pragma unroll
  for (int r = 0; r < 4; ++r) {
    int rb = rowBase + g * 4 + r;
    float mean = s[r] * (1.0f / 128.0f);
    float var  = qq[r] * (1.0f / 128.0f) - mean * mean;
    float inv  = 1.0f / (sqrtf(var + 1e-5f) + 1e-5f);   // ref: sqrt(var+eps)+eps
    if (rb < DEG_COUNT) {
      size_t grow = (size_t)d * DEG_COUNT + rb;
#pragma unroll
      for (int ct = 0; ct < 8; ++ct) {
        float v = gam[ct] * ((acc[ct][r] - mean) * inv) + bet[ct];
        __builtin_nontemporal_store(v, out0 + grow * 128 + ct * 16 + m16);
      }
    }
  }
}

// ---------------------------------------------------------------------------
// Counting sort by membership — atomic-contention-free 3-phase version.
// ---------------------------------------------------------------------------
__global__ __launch_bounds__(256) void k_hist2(const int* __restrict__ membership,
                                               int* __restrict__ blockHist) {
  __shared__ int bins[BATCH];
  int tid = threadIdx.x;
  if (tid < BATCH) bins[tid] = 0;
  __syncthreads();
  const int chunk = (N_ATOMS + SORT_BLOCKS - 1) / SORT_BLOCKS;
  int lo = blockIdx.x * chunk, hi = min(lo + chunk, N_ATOMS);
  for (int i = lo + tid; i < hi; i += 256)
    atomicAdd(&bins[membership[i]], 1);
  __syncthreads();
  if (tid < BATCH) blockHist[blockIdx.x * BATCH + tid] = bins[tid];
}

__global__ __launch_bounds__(128) void k_scan2(const int* __restrict__ blockHist,
                                               int* __restrict__ off,     // [SORT_BLOCKS][128]
                                               int* __restrict__ base,
                                               int* __restrict__ hist) {
  int m = threadIdx.x;
  int tot = 0;
  for (int b = 0; b < SORT_BLOCKS; ++b) tot += blockHist[b * BATCH + m];
  hist[m] = tot;
  __shared__ int t[BATCH];
  t[m] = tot;
  __syncthreads();
  int acc = 0;
  for (int i = 0; i < m; ++i) acc += t[i];
  base[m] = acc;
  int run = acc;
  for (int b = 0; b < SORT_BLOCKS; ++b) {
    off[b * BATCH + m] = run;
    run += blockHist[b * BATCH + m];
  }
}

__global__ __launch_bounds__(256) void k_scatter2(const int* __restrict__ membership,
                                                  const int* __restrict__ off,
                                                  int* __restrict__ perm) {
  __shared__ int bins[BATCH];
  int tid = threadIdx.x;
  if (tid < BATCH) bins[tid] = off[blockIdx.x * BATCH + tid];
  __syncthreads();
  const int chunk = (N_ATOMS + SORT_BLOCKS - 1) / SORT_BLOCKS;
  int lo = blockIdx.x * chunk, hi = min(lo + chunk, N_ATOMS);
  for (int i = lo + tid; i < hi; i += 256) {
    int m = membership[i];
    int pos = atomicAdd(&bins[m], 1);
    perm[pos] = i;
  }
}

// ---------------------------------------------------------------------------
// K_mreduce: ONE perm pass doing BOTH segment-max(xn) AND per-(molecule,
// degree) atom sums + counts (was k_reduce + k_msum: two passes over the
// same perm ranges). All big reads are read-once -> nt loads (no L3 thrash).
// 512 blocks = 128 molecules x 4 slices. Wave-private LDS sum tables (no
// atomics; d is wave-uniform per row).
// ---------------------------------------------------------------------------
__global__ __launch_bounds__(512) void k_mreduce(
    const f32x2* __restrict__ xnV,          // out0 as f32x2
    const unsigned* __restrict__ atomsU,
    const int* __restrict__ perm,
    const int* __restrict__ base,
    const int* __restrict__ hist,
    float* __restrict__ Spart,      // [4][128][11][128]
    int* __restrict__ cntPart,      // [4][128][11]
    float2* __restrict__ pmax4)     // [4][128][64] float2
{
  const int m = blockIdx.x >> 2;
  const int s = blockIdx.x & 3;
  const int b0 = base[m], cnt = hist[m];
  const int lo = b0 + (cnt * s) / 4;
  const int hi = b0 + (cnt * (s + 1)) / 4;
  const int wave = threadIdx.x >> 6, lane = threadIdx.x & 63;

  __shared__ float S[8][11][128];   // physical col p: p<64 -> col 2p, else 2(p-64)+1
  __shared__ int C[8][11];
  __shared__ float2 maxT[8][64];
  for (int e = lane; e < 11 * 128; e += 64) S[wave][e >> 7][e & 127] = 0.f;
  if (lane < 11) C[wave][lane] = 0;
  __syncthreads();

  const float NEG_INF = __int_as_float((int)NEG_INF_BITS);
  float mx0 = NEG_INF, mx1 = NEG_INF;

  for (int i = lo + wave; i < hi; i += 8) {
    int r = perm[i];
    int d = r / DEG_COUNT;                      // wave-uniform
    f32x2 x = __builtin_nontemporal_load(xnV + (size_t)r * 64 + lane);
    unsigned a = __builtin_nontemporal_load(atomsU + (size_t)r * 64 + lane);
    mx0 = fmaxf(mx0, x[0]);
    mx1 = fmaxf(mx1, x[1]);
    S[wave][d][lane]      += bf2f((unsigned short)(a & 0xffff));
    S[wave][d][64 + lane] += bf2f((unsigned short)(a >> 16));
    if (lane == 0) C[wave][d]++;
  }
  maxT[wave][lane] = make_float2(mx0, mx1);
  __syncthreads();

  if (threadIdx.x < 64) {
    int l = threadIdx.x;
    float2 mm = maxT[0][l];
#pragma unroll
    for (int w = 1; w < 8; ++w) {
      float2 b = maxT[w][l]; mm.x = fmaxf(mm.x, b.x); mm.y = fmaxf(mm.y, b.y);
    }
    pmax4[(s * 128 + m) * 64 + l] = mm;
  }
  for (int e = threadIdx.x; e < 11 * 128; e += 512) {
    int d = e >> 7, p = e & 127;
    float t = 0.f;
#pragma unroll
    for (int w = 0; w < 8; ++w) t += S[w][d][p];
    int col = (p < 64) ? (2 * p) : (2 * (p - 64) + 1);   // de-permute
    Spart[(((size_t)s * 128 + m) * 11 + d) * 128 + col] = t;
  }
  if (threadIdx.x < 11) {
    int t = 0;
#pragma unroll
    for (int w = 0; w < 8; ++w) t += C[w][threadIdx.x];
    cntPart[((size_t)s * 128 + m) * 11 + threadIdx.x] = t;
  }
}

// ---------------------------------------------------------------------------
// K_ynfinal: yn = LN( sum_d S[m,d] @ Wg_d + cnt[m,d]*bg_d ) -> out1, and
// merge 4 max slices -> out2. 128 blocks x 128 threads.
// ---------------------------------------------------------------------------
__global__ __launch_bounds__(128) void k_ynfinal(
    const float* __restrict__ Spart,
    const int* __restrict__ cntPart,
    const float* __restrict__ W,
    const float* __restrict__ b,
    const float* __restrict__ gamma,
    const float* __restrict__ beta,
    const float* __restrict__ pmax4,        // [4][128][128]
    float* __restrict__ out1,
    float* __restrict__ out2)
{
  int m = blockIdx.x;
  int j = threadIdx.x;

  float g = __int_as_float((int)NEG_INF_BITS);
#pragma unroll
  for (int sl = 0; sl < 4; ++sl)
    g = fmaxf(g, pmax4[(sl * 128 + m) * 128 + j]);
  out2[m * 128 + j] = g;

  __shared__ float Sm[11][128];
  __shared__ float cw[11];
  for (int e = j; e < 11 * 128; e += 128) {
    int d = e >> 7, c = e & 127;
    float t = 0.f;
#pragma unroll
    for (int sl = 0; sl < 4; ++sl)
      t += Spart[(((size_t)sl * 128 + m) * 11 + d) * 128 + c];
    Sm[d][c] = t;
  }
  if (j < 11) {
    int t = 0;
#pragma unroll
    for (int sl = 0; sl < 4; ++sl) t += cntPart[((size_t)sl * 128 + m) * 11 + j];
    cw[j] = (float)t;
  }
  __syncthreads();

  float acc = 0.f;
  for (int d = 0; d < 11; ++d) {
    int wi = (d >= 1) ? (20 + d) : 31;
    const float* Wd = W + wi * 16384;
    float a0 = 0.f, a1 = 0.f, a2 = 0.f, a3 = 0.f;
    for (int k = 0; k < 128; k += 4) {
      a0 += Sm[d][k]     * Wd[k * 128 + j];
      a1 += Sm[d][k + 1] * Wd[(k + 1) * 128 + j];
      a2 += Sm[d][k + 2] * Wd[(k + 2) * 128 + j];
      a3 += Sm[d][k + 3] * Wd[(k + 3) * 128 + j];
    }
    acc += (a0 + a1) + (a2 + a3);
    acc += cw[d] * b[wi * 128 + j];
  }

  float ws_ = acc, wq = acc * acc;
#pragma unroll
  for (int off = 32; off >= 1; off >>= 1) {
    ws_ += __shfl_xor(ws_, off, 64);
    wq  += __shfl_xor(wq, off, 64);
  }
  __shared__ float red[4];
  int wave = j >> 6, lane = j & 63;
  if (lane == 0) { red[wave * 2] = ws_; red[wave * 2 + 1] = wq; }
  __syncthreads();
  float Ssum = red[0] + red[2], Q = red[1] + red[3];
  float mean = Ssum * (1.f / 128.f);
  float var = Q * (1.f / 128.f) - mean * mean;
  float inv = 1.f / (sqrtf(var + 1e-5f) + 1e-5f);
  out1[m * 128 + j] = gamma[j] * ((acc - mean) * inv) + beta[j];
}

// ---------------------------------------------------------------------------
extern "C" void kernel_launch(void* const* d_in, const int* in_sizes, int n_in,
                              void* d_out, int out_size, void* d_ws, size_t ws_size,
                              hipStream_t stream) {
  const float* atoms = (const float*)d_in[0];
  // d_in[1] = deg_slice (unused; buckets are static)
  const int* membership = (const int*)d_in[2];
  AdjPtrs adj;
  for (int i = 0; i < 10; ++i) adj.p[i] = (const int*)d_in[3 + i];
  const float* W     = (const float*)d_in[13];
  const float* b     = (const float*)d_in[14];
  const float* gamma = (const float*)d_in[15];
  const float* beta  = (const float*)d_in[16];

  char* ws = (char*)d_ws;
  size_t off = 0;
  unsigned short* atomsBf = (unsigned short*)(ws + off); off += (size_t)N_ATOMS * 128 * 2;
  unsigned short* BcatT   = (unsigned short*)(ws + off); off += (size_t)11 * 128 * 256 * 2;
  float* biascat          = (float*)(ws + off);          off += (size_t)11 * 128 * 4;
  int* perm               = (int*)(ws + off);            off += (size_t)N_ATOMS * 4;
  int* hist               = (int*)(ws + off);            off += 512;
  int* base_              = (int*)(ws + off);            off += 512;
  int* blockHist          = (int*)(ws + off);            off += (size_t)SORT_BLOCKS * BATCH * 4;
  int* offTab             = (int*)(ws + off);            off += (size_t)SORT_BLOCKS * BATCH * 4;
  float* Spart            = (float*)(ws + off);          off += (size_t)4 * 128 * 11 * 128 * 4;
  int* cntPart            = (int*)(ws + off);            off += (size_t)4 * 128 * 11 * 4;
  float* pmax4            = (float*)(ws + off);          off += (size_t)4 * 128 * 128 * 4;

  float* out0 = (float*)d_out;
  float* out1 = out0 + (size_t)N_ATOMS * 128;
  float* out2 = out1 + 16384;

  hipLaunchKernelGGL(k_cast, dim3(N_ATOMS * 128 / 4 / 256), dim3(256), 0, stream,
                     (const f32x4*)atoms, (ushort4*)atomsBf);
  hipLaunchKernelGGL(k_build_b, dim3((11 * 128 * 256 + 255) / 256), dim3(256), 0, stream, W, BcatT);
  hipLaunchKernelGGL(k_build_bias, dim3((11 * 128 + 255) / 256), dim3(256), 0, stream, b, biascat);
  // counting sort (zero global atomics)
  hipLaunchKernelGGL(k_hist2, dim3(SORT_BLOCKS), dim3(256), 0, stream, membership, blockHist);
  hipLaunchKernelGGL(k_scan2, dim3(1), dim3(128), 0, stream, blockHist, offTab, base_, hist);
  hipLaunchKernelGGL(k_scatter2, dim3(SORT_BLOCKS), dim3(256), 0, stream, membership, offTab, perm);
  // fused nsum + activated GEMM + LN (nt out0 stores)
  hipLaunchKernelGGL(k_gemm, dim3(236, 11), dim3(512), 0, stream,
                     atomsBf, adj, BcatT, biascat, gamma, beta, out0);
  // fused segment-max(xn) + per-(mol,deg) atom sums (single perm pass)
  hipLaunchKernelGGL(k_mreduce, dim3(512), dim3(512), 0, stream,
                     (const f32x2*)out0, (const unsigned*)atomsBf, perm, base_, hist,
                     Spart, cntPart, (float2*)pmax4);
  // yn (algebraic gathered path) + max merge
  hipLaunchKernelGGL(k_ynfinal, dim3(128), dim3(128), 0, stream,
                     Spart, cntPart, W, b, gamma, beta, pmax4, out1, out2);
}